// Round 19
// baseline (289.604 us; speedup 1.0000x reference)
//
#include <hip/hip_runtime.h>
#include <hip/hip_cooperative_groups.h>
#include <math.h>

namespace cg = cooperative_groups;

#define FF 256
#define CC 100000
#define PMARG 0.2f
#define NMARG 0.3f
#define NCT 6250                 // col-tiles of 16 (6250*16 == CC exactly)
#define NCTP 6272                // padded partial stride (multiple of 64)
#define NBLK 512                 // cooperative grid: 2 blocks/CU guaranteed
#define CAST_N 3200000           // CC*FF/8 16B-chunks
#define W_A 0                    // ws floats: A-pack bf16 frags (32KB)
#define W_GRAM 8192              // Gram 64x64 f32
#define W_SE 12288               // 64 row exp-sums
#define W_PART 12352             // coop: [64][NCTP] partials; fb: [NPART][64]
#define W_VB_BYTES 2000000ULL    // Vbf16 row-major: 51.2MB
#define WS_NEED (W_VB_BYTES + (size_t)CC * FF * 2)
// fallback consts
#define NGB 1563
#define NPART (NGB * 4)
#define RPB 12500

typedef __attribute__((ext_vector_type(8))) short short8;   // 8 bf16
typedef __attribute__((ext_vector_type(4))) float f32x4;

__device__ __forceinline__ float wredf(float v) {
#pragma unroll
    for (int s = 1; s < 64; s <<= 1) v += __shfl_xor(v, s, 64);
    return v;
}
__device__ __forceinline__ short f2bf(float f) {
    unsigned u = __float_as_uint(f);
    unsigned r = (u + 0x7fffu + ((u >> 16) & 1u)) >> 16;
    return (short)r;
}
__device__ __forceinline__ short8 pack8(float4 a, float4 b) {
    short8 o;
    o[0] = f2bf(a.x); o[1] = f2bf(a.y); o[2] = f2bf(a.z); o[3] = f2bf(a.w);
    o[4] = f2bf(b.x); o[5] = f2bf(b.y); o[6] = f2bf(b.z); o[7] = f2bf(b.w);
    return o;
}
__device__ __forceinline__ short8 pack8v(f32x4 a, f32x4 b) {
    short8 o;
    o[0] = f2bf(a[0]); o[1] = f2bf(a[1]); o[2] = f2bf(a[2]); o[3] = f2bf(a[3]);
    o[4] = f2bf(b[0]); o[5] = f2bf(b[1]); o[6] = f2bf(b[2]); o[7] = f2bf(b[3]);
    return o;
}
__device__ __forceinline__ float dot4(float4 a, float4 b) {
    return a.x * b.x + a.y * b.y + a.z * b.z + a.w * b.w;
}
__device__ __forceinline__ bool mask_at(const void* p, int idx, int mode) {
    if (mode == 0) return ((const int*)p)[idx] != 0;
    if (mode == 1) return ((const float*)p)[idx] != 0.f;
    return ((const unsigned char*)p)[idx] != 0;
}

// ======================= cooperative mega-kernel =======================
// P0: Gram rows (blocks 0..63) + A-pack (block 64) + linear V->bf16 cast (all)
// P1: GEMM from Vbf16 (R18 k_gemmb math, grid-strided waves)
// P2: partial combine (blocks 0..63, coalesced transposed partials)
// P3: scalar tail on block 0 (G in LDS, masks as per-lane 64-bit registers)
__global__ __launch_bounds__(256) void k_all(const float* __restrict__ in,
                                             const float* __restrict__ V,
                                             const int* __restrict__ targets,
                                             const void* __restrict__ pmask,
                                             const void* __restrict__ nmask,
                                             float* __restrict__ logits,
                                             float* __restrict__ ws) {
    cg::grid_group grid = cg::this_grid();
    __shared__ float sLds[4096];          // 16KB: sS (P0/P2), sG (P3)
    int tid = threadIdx.x;
    int b = blockIdx.x;
    const float4* __restrict__ in4 = (const float4*)in;

    // ---------------- P0 ----------------
    if (b < 64) {
        int r = b, c = tid & 63, part = tid >> 6;
        float s = 0.f;
#pragma unroll
        for (int i = 0; i < 16; ++i) {
            int kq = part * 16 + i;
            s += dot4(in4[r * 64 + kq], in4[c * 64 + kq]);
        }
        sLds[tid] = s;
        __syncthreads();
        if (tid < 64)
            ws[W_GRAM + r * 64 + tid] =
                sLds[tid] + sLds[64 + tid] + sLds[128 + tid] + sLds[192 + tid];
        __syncthreads();
    } else if (b == 64) {
        short8* __restrict__ wsa = (short8*)(ws + W_A);
#pragma unroll
        for (int i = 0; i < 8; ++i) {
            int idx = i * 256 + tid;      // (mt*8+ks)*64 + lane
            int lane = idx & 63;
            int ks = (idx >> 6) & 7;
            int mt = idx >> 9;
            int row = mt * 16 + (lane & 15);
            int kq = ks * 8 + (lane >> 4) * 2;
            wsa[idx] = pack8(in4[row * 64 + kq], in4[row * 64 + kq + 1]);
        }
    }
    {   // linear cast, all blocks: read 32B linear, write 16B linear
        short8* __restrict__ vb = (short8*)((char*)ws + W_VB_BYTES);
        const float4* __restrict__ Vf = (const float4*)V;
        for (int i = b * 256 + tid; i < CAST_N; i += NBLK * 256) {
            float4 x = Vf[(size_t)i * 2];
            float4 y = Vf[(size_t)i * 2 + 1];
            vb[i] = pack8(x, y);
        }
    }
    grid.sync();

    // ---------------- P1: GEMM ----------------
    {
        int lane = tid & 63, w = tid >> 6;
        int g = lane >> 4, c4 = lane & 15;
        const short8* __restrict__ ap = (const short8*)(ws + W_A) + lane;
        const short8* __restrict__ vbb = (const short8*)((char*)ws + W_VB_BYTES);
        for (int ct = b * 4 + w; ct < NCT; ct += NBLK * 4) {
            const short8* __restrict__ vb = vbb + (size_t)(ct * 16 + c4) * 32 + g;
            short8 bfr[8];
#pragma unroll
            for (int ks = 0; ks < 8; ++ks) bfr[ks] = vb[ks * 4];
            f32x4 acc[4];
#pragma unroll
            for (int mt = 0; mt < 4; ++mt) acc[mt] = (f32x4){0.f, 0.f, 0.f, 0.f};
#pragma unroll
            for (int ks = 0; ks < 8; ++ks)
#pragma unroll
                for (int mt = 0; mt < 4; ++mt) {
                    short8 a = ap[(mt * 8 + ks) * 64];
                    acc[mt] = __builtin_amdgcn_mfma_f32_16x16x32_bf16(
                        a, bfr[ks], acc[mt], 0, 0, 0);
                }
            int col = ct * 16 + c4;
#pragma unroll
            for (int mt = 0; mt < 4; ++mt)
#pragma unroll
                for (int r = 0; r < 4; ++r) {
                    int row = mt * 16 + g * 4 + r;
                    float lg = acc[mt][r];
                    logits[(size_t)row * CC + col] = lg;
                    float e = expf(lg);            // |logit| small, safe
                    e += __shfl_xor(e, 1, 64); e += __shfl_xor(e, 2, 64);
                    e += __shfl_xor(e, 4, 64); e += __shfl_xor(e, 8, 64);
                    if (c4 == 0) ws[W_PART + (size_t)row * NCTP + ct] = e;
                }
        }
    }
    grid.sync();

    // ---------------- P2: combine ----------------
    if (b < 64) {
        int row = b;
        const float* __restrict__ P = ws + W_PART + (size_t)row * NCTP;
        float s = 0.f;
        for (int ct = tid; ct < NCT; ct += 256) s += P[ct];   // coalesced
        sLds[tid] = s;
        __syncthreads();
        if (tid < 128) sLds[tid] += sLds[tid + 128];
        __syncthreads();
        if (tid < 64) {
            float v = sLds[tid] + sLds[tid + 64];
            v = wredf(v);
            if (tid == 0) ws[W_SE + row] = v;
        }
        __syncthreads();
    }
    grid.sync();

    // ---------------- P3: tail (block 0) ----------------
    if (b != 0) return;
    {
        const float4* __restrict__ G4 = (const float4*)(ws + W_GRAM);
        float4* sG4 = (float4*)sLds;
#pragma unroll
        for (int i = 0; i < 4; ++i) sG4[i * 256 + tid] = G4[i * 256 + tid];
    }
    __syncthreads();
    if (tid >= 64) return;
    int lane = tid;

    float mySe = ws[W_SE + lane];
    int tgt = targets[lane];
    float myLogit = logits[(size_t)lane * CC + tgt];

    // mode detect (identical semantics to all prior rounds)
    const unsigned int* pw = (const unsigned int*)pmask;
    int okInt = 1, okFlt = 1;
#pragma unroll
    for (int i = 0; i < 16; ++i) {
        unsigned int wv = pw[lane * 16 + i];
        okInt = okInt && (wv <= 1u);
        okFlt = okFlt && (wv == 0u || wv == 0x3f800000u);
    }
    int mode = __all(okInt) ? 0 : (__all(okFlt) ? 1 : 2);

    // pack masks into per-lane 64-bit registers (removes memory from j-loops)
    unsigned long long pmb = 0ull, nmb = 0ull;
    for (int j = 0; j < 64; ++j) {
        if (mask_at(pmask, lane * 64 + j, mode)) pmb |= 1ull << j;
        if (mask_at(nmask, lane * 64 + j, mode)) nmb |= 1ull << j;
    }

    float lse = logf(mySe);
    float nll = lse - myLogit;
    float rinv = rsqrtf(sLds[lane * 64 + lane]);

    float minp = INFINITY, maxthd = -INFINITY;
    for (int j = 0; j < 64; ++j) {
        float rj = __shfl(rinv, j, 64);
        float sim = sLds[lane * 64 + j] * rinv * rj;
        sim = fminf(1.f, fmaxf(-1.f, sim));
        if (j != lane) {
            bool pm = (pmb >> j) & 1ull;
            float ps = pm ? sim : 2.0f;
            minp = fminf(minp, ps);
            maxthd = fmaxf(maxthd, pm ? sim : -2.0f);   // sentinel 2.0 -> -2.0
        }
    }
    float n_thrd = minp - NMARG;
    float p_thrd = maxthd - PMARG;

    float hps = 0.f, hns = 0.f, hpc = 0.f, hnc = 0.f;
    for (int j = 0; j < 64; ++j) {
        float rj = __shfl(rinv, j, 64);
        float sim = sLds[lane * 64 + j] * rinv * rj;
        sim = fminf(1.f, fmaxf(-1.f, sim));
        if (j != lane) {
            bool pm = (pmb >> j) & 1ull;
            bool nm = (nmb >> j) & 1ull;
            float ps = pm ? sim : 2.0f;
            float ns = nm ? sim : 2.0f;
            if (ps < p_thrd) { hps += log1pf(expf(-ps)); hpc += 1.f; }
            if (ns < n_thrd) { hns += log1pf(expf(-ns)); hnc += 1.f; }
        }
    }

    float snll = wredf(nll);
    float shps = wredf(hps);
    float shns = wredf(hns);
    float shpc = wredf(hpc);
    float shnc = wredf(hnc);
    if (lane == 0) {
        float bu = snll * (1.f / 64.f);
        float hp = shpc > 0.f ? shps / shpc : 0.f;
        float hn = shnc > 0.f ? shns / shnc : 0.f;
        float* out = logits - 1;          // out[0] precedes logits
        out[0] = bu + hp + hn;
    }
}

// ===================== fallback path (R18, passing) =====================
__global__ __launch_bounds__(256) void k_produce(const float* __restrict__ in,
                                                 const float* __restrict__ V,
                                                 float* __restrict__ ws) {
    int tid = threadIdx.x;
    int b = blockIdx.x;
    const float4* __restrict__ in4 = (const float4*)in;
    if (b < 64) {
        __shared__ float sS[256];
        int r = b, c = tid & 63, part = tid >> 6;
        float s = 0.f;
#pragma unroll
        for (int i = 0; i < 16; ++i) {
            int kq = part * 16 + i;
            s += dot4(in4[r * 64 + kq], in4[c * 64 + kq]);
        }
        sS[tid] = s;
        __syncthreads();
        if (tid < 64)
            ws[W_GRAM + r * 64 + tid] =
                sS[tid] + sS[64 + tid] + sS[128 + tid] + sS[192 + tid];
        return;
    }
    if (b == 64) {
        short8* __restrict__ wsa = (short8*)(ws + W_A);
#pragma unroll
        for (int i = 0; i < 8; ++i) {
            int idx = i * 256 + tid;
            int lane = idx & 63;
            int ks = (idx >> 6) & 7;
            int mt = idx >> 9;
            int row = mt * 16 + (lane & 15);
            int kq = ks * 8 + (lane >> 4) * 2;
            wsa[idx] = pack8(in4[row * 64 + kq], in4[row * 64 + kq + 1]);
        }
        return;
    }
    int i = (b - 65) * 256 + tid;
    const float4* __restrict__ s = (const float4*)V + (size_t)i * 2;
    float4 x = s[0];
    float4 y = s[1];
    short8* __restrict__ vb = (short8*)((char*)ws + W_VB_BYTES);
    vb[i] = pack8(x, y);
}

__global__ __launch_bounds__(256, 2) void k_gemmb(const float* __restrict__ ws_in,
                                                  float* __restrict__ logits,
                                                  float* __restrict__ ws) {
    int tid = threadIdx.x;
    int lane = tid & 63, w = tid >> 6;
    int ct = blockIdx.x * 4 + w;
    int g = lane >> 4, c4 = lane & 15;
    bool ctv = ct < NCT;
    int cts = ctv ? ct : 0;
    const short8* __restrict__ vb =
        (const short8*)((const char*)ws_in + W_VB_BYTES) +
        (size_t)(cts * 16 + c4) * 32 + g;
    short8 bfr[8];
#pragma unroll
    for (int ks = 0; ks < 8; ++ks) bfr[ks] = vb[ks * 4];
    const short8* __restrict__ ap = (const short8*)(ws_in + W_A) + lane;
    f32x4 acc[4];
#pragma unroll
    for (int mt = 0; mt < 4; ++mt) acc[mt] = (f32x4){0.f, 0.f, 0.f, 0.f};
#pragma unroll
    for (int ks = 0; ks < 8; ++ks)
#pragma unroll
        for (int mt = 0; mt < 4; ++mt) {
            short8 a = ap[(mt * 8 + ks) * 64];
            acc[mt] = __builtin_amdgcn_mfma_f32_16x16x32_bf16(a, bfr[ks],
                                                              acc[mt], 0, 0, 0);
        }
    int col = ct * 16 + c4;
    float* __restrict__ P = ws + W_PART + (size_t)(blockIdx.x * 4 + w) * 64;
#pragma unroll
    for (int mt = 0; mt < 4; ++mt)
#pragma unroll
        for (int r = 0; r < 4; ++r) {
            int row = mt * 16 + g * 4 + r;
            float lg = acc[mt][r];
            if (ctv) logits[(size_t)row * CC + col] = lg;
            float e = ctv ? expf(lg) : 0.f;
            e += __shfl_xor(e, 1, 64); e += __shfl_xor(e, 2, 64);
            e += __shfl_xor(e, 4, 64); e += __shfl_xor(e, 8, 64);
            if (c4 == 0) P[row] = e;
        }
}

__global__ __launch_bounds__(256) void k_comb(const float* __restrict__ ws_in,
                                              float* __restrict__ ws) {
    __shared__ float sS[256];
    int row = blockIdx.x;
    int tid = threadIdx.x;
    const float* __restrict__ P = ws_in + W_PART;
    float s = 0.f;
    for (int b = tid; b < NPART; b += 256) s += P[(size_t)b * 64 + row];
    sS[tid] = s;
    __syncthreads();
    if (tid < 128) sS[tid] += sS[tid + 128];
    __syncthreads();
    if (tid < 64) {
        float v = sS[tid] + sS[tid + 64];
        v = wredf(v);
        if (tid == 0) ws[W_SE + row] = v;
    }
}

__global__ __launch_bounds__(256) void k_final(const int* __restrict__ targets,
                                               const void* __restrict__ pmask,
                                               const void* __restrict__ nmask,
                                               const float* __restrict__ logits,
                                               const float* __restrict__ ws,
                                               float* __restrict__ out) {
    __shared__ float sG[4096];
    int tid = threadIdx.x;
    float myLogit = 0.f, mySe = 0.f;
    if (tid < 64) {
        int tgt = targets[tid];
        myLogit = logits[(size_t)tid * CC + tgt];
        mySe = ws[W_SE + tid];
    }
    {
        const float4* __restrict__ G4 = (const float4*)(ws + W_GRAM);
        float4* sG4 = (float4*)sG;
#pragma unroll
        for (int i = 0; i < 4; ++i) sG4[tid + i * 256] = G4[tid + i * 256];
    }
    __syncthreads();
    if (tid >= 64) return;
    int lane = tid;

    const unsigned int* pw = (const unsigned int*)pmask;
    int okInt = 1, okFlt = 1;
#pragma unroll
    for (int i = 0; i < 16; ++i) {
        unsigned int wv = pw[lane * 16 + i];
        okInt = okInt && (wv <= 1u);
        okFlt = okFlt && (wv == 0u || wv == 0x3f800000u);
    }
    int mode = __all(okInt) ? 0 : (__all(okFlt) ? 1 : 2);

    unsigned long long pmb = 0ull, nmb = 0ull;
    for (int j = 0; j < 64; ++j) {
        if (mask_at(pmask, lane * 64 + j, mode)) pmb |= 1ull << j;
        if (mask_at(nmask, lane * 64 + j, mode)) nmb |= 1ull << j;
    }

    float lse = logf(mySe);
    float nll = lse - myLogit;
    float rinv = rsqrtf(sG[lane * 64 + lane]);

    float minp = INFINITY, maxthd = -INFINITY;
    for (int j = 0; j < 64; ++j) {
        float rj = __shfl(rinv, j, 64);
        float sim = sG[lane * 64 + j] * rinv * rj;
        sim = fminf(1.f, fmaxf(-1.f, sim));
        if (j != lane) {
            bool pm = (pmb >> j) & 1ull;
            float ps = pm ? sim : 2.0f;
            minp = fminf(minp, ps);
            maxthd = fmaxf(maxthd, pm ? sim : -2.0f);
        }
    }
    float n_thrd = minp - NMARG;
    float p_thrd = maxthd - PMARG;

    float hps = 0.f, hns = 0.f, hpc = 0.f, hnc = 0.f;
    for (int j = 0; j < 64; ++j) {
        float rj = __shfl(rinv, j, 64);
        float sim = sG[lane * 64 + j] * rinv * rj;
        sim = fminf(1.f, fmaxf(-1.f, sim));
        if (j != lane) {
            bool pm = (pmb >> j) & 1ull;
            bool nm = (nmb >> j) & 1ull;
            float ps = pm ? sim : 2.0f;
            float ns = nm ? sim : 2.0f;
            if (ps < p_thrd) { hps += log1pf(expf(-ps)); hpc += 1.f; }
            if (ns < n_thrd) { hns += log1pf(expf(-ns)); hnc += 1.f; }
        }
    }

    float snll = wredf(nll);
    float shps = wredf(hps);
    float shns = wredf(hns);
    float shpc = wredf(hpc);
    float shnc = wredf(hnc);
    if (lane == 0) {
        float bu = snll * (1.f / 64.f);
        float hp = shpc > 0.f ? shps / shpc : 0.f;
        float hn = shnc > 0.f ? shns / shnc : 0.f;
        out[0] = bu + hp + hn;
    }
}

extern "C" void kernel_launch(void* const* d_in, const int* in_sizes, int n_in,
                              void* d_out, int out_size, void* d_ws, size_t ws_size,
                              hipStream_t stream) {
    const float* inputs = (const float*)d_in[0];
    const int* targets  = (const int*)d_in[1];
    const void* pmask   = d_in[2];
    const void* nmask   = d_in[3];
    const float* V      = (const float*)d_in[4];
    float* out = (float*)d_out;      // out[0] = loss
    float* logits = out + 1;         // out[1..] = logits [64][100000] row-major
    float* ws = (float*)d_ws;        // A-pack | Gram | se | partials | Vbf16

    if (ws_size >= WS_NEED) {
        void* args[] = {(void*)&inputs, (void*)&V, (void*)&targets,
                        (void*)&pmask, (void*)&nmask, (void*)&logits, (void*)&ws};
        hipError_t err = hipLaunchCooperativeKernel(
            (const void*)k_all, dim3(NBLK), dim3(256), args, 0, stream);
        if (err == hipSuccess) return;
        // fall through to separate-kernel path on any launch failure
        hipLaunchKernelGGL(k_produce, dim3(65 + RPB), dim3(256), 0, stream,
                           inputs, V, ws);
        hipLaunchKernelGGL(k_gemmb, dim3(NGB), dim3(256), 0, stream,
                           ws, logits, ws);
        hipLaunchKernelGGL(k_comb, dim3(64), dim3(256), 0, stream, ws, ws);
        hipLaunchKernelGGL(k_final, dim3(1), dim3(256), 0, stream,
                           targets, pmask, nmask, logits, ws, out);
        return;
    }
    // ws too small (never observed): produce prep-only + direct-V path
    hipLaunchKernelGGL(k_produce, dim3(65), dim3(256), 0, stream, inputs, V, ws);
    hipLaunchKernelGGL(k_gemmb, dim3(NGB), dim3(256), 0, stream, ws, logits, ws);
    hipLaunchKernelGGL(k_comb, dim3(64), dim3(256), 0, stream, ws, ws);
    hipLaunchKernelGGL(k_final, dim3(1), dim3(256), 0, stream,
                       targets, pmask, nmask, logits, ws, out);
}

// Round 20
// 85.559 us; speedup vs baseline: 3.3848x; 3.3848x over previous
//
#include <hip/hip_runtime.h>
#include <math.h>

#define FF 256
#define CC 100000
#define PMARG 0.2f
#define NMARG 0.3f
#define NCT 6250                 // col-tiles of 16 (6250*16 == CC exactly)
#define NGB 3125                 // gemm blocks: 2 ct x 2 k-halves (4 waves)
#define W_A 0                    // ws floats: A-pack bf16 frags (32KB)
#define W_GRAM 8192              // Gram 64x64 f32
#define W_SE 12288               // 64 row exp-sums
#define W_PART 12352             // per-ct exp partials: NCT*64 floats

typedef __attribute__((ext_vector_type(8))) short short8;   // 8 bf16 = 4 VGPR
typedef __attribute__((ext_vector_type(4))) float f32x4;

__device__ __forceinline__ float wredf(float v) {
#pragma unroll
    for (int s = 1; s < 64; s <<= 1) v += __shfl_xor(v, s, 64);
    return v;
}
__device__ __forceinline__ short f2bf(float f) {
    unsigned u = __float_as_uint(f);
    unsigned r = (u + 0x7fffu + ((u >> 16) & 1u)) >> 16;
    return (short)r;
}
__device__ __forceinline__ short8 pack8(float4 a, float4 b) {
    short8 o;
    o[0] = f2bf(a.x); o[1] = f2bf(a.y); o[2] = f2bf(a.z); o[3] = f2bf(a.w);
    o[4] = f2bf(b.x); o[5] = f2bf(b.y); o[6] = f2bf(b.z); o[7] = f2bf(b.w);
    return o;
}
__device__ __forceinline__ short8 pack8v(f32x4 a, f32x4 b) {
    short8 o;
    o[0] = f2bf(a[0]); o[1] = f2bf(a[1]); o[2] = f2bf(a[2]); o[3] = f2bf(a[3]);
    o[4] = f2bf(b[0]); o[5] = f2bf(b[1]); o[6] = f2bf(b[2]); o[7] = f2bf(b[3]);
    return o;
}
__device__ __forceinline__ float dot4(float4 a, float4 b) {
    return a.x * b.x + a.y * b.y + a.z * b.z + a.w * b.w;
}
__device__ __forceinline__ bool mask_at(const void* p, int idx, int mode) {
    if (mode == 0) return ((const int*)p)[idx] != 0;
    if (mode == 1) return ((const float*)p)[idx] != 0.f;
    return ((const unsigned char*)p)[idx] != 0;
}

// blocks 0..63: Gram row b (f32, accuracy-critical); block 64: A-pack
__global__ __launch_bounds__(256) void k_prep(const float* __restrict__ in,
                                              float* __restrict__ ws) {
    int tid = threadIdx.x;
    int b = blockIdx.x;
    const float4* __restrict__ in4 = (const float4*)in;
    if (b < 64) {
        __shared__ float sS[256];
        int r = b, c = tid & 63, part = tid >> 6;
        float s = 0.f;
#pragma unroll
        for (int i = 0; i < 16; ++i) {
            int kq = part * 16 + i;
            s += dot4(in4[r * 64 + kq], in4[c * 64 + kq]);
        }
        sS[tid] = s;
        __syncthreads();
        if (tid < 64)
            ws[W_GRAM + r * 64 + tid] =
                sS[tid] + sS[64 + tid] + sS[128 + tid] + sS[192 + tid];
        return;
    }
    short8* __restrict__ wsa = (short8*)(ws + W_A);
#pragma unroll
    for (int i = 0; i < 8; ++i) {
        int idx = i * 256 + tid;          // (mt*8+ks)*64 + lane
        int lane = idx & 63;
        int ks = (idx >> 6) & 7;
        int mt = idx >> 9;
        int row = mt * 16 + (lane & 15);
        int kq = ks * 8 + (lane >> 4) * 2;
        wsa[idx] = pack8(in4[row * 64 + kq], in4[row * 64 + kq + 1]);
    }
}

// Split-K GEMM, single pass over V-f32: block = 4 waves = 2 ct x 2 k-halves.
// Each wave loads only ITS K-half (8 loads -> the chain length that measured
// fast in gemm3v) of its ct's 16 V rows, does 16 MFMA; kh=1 wave deposits
// accumulators in LDS, one barrier, kh=0 wave sums + epilogue. V read once,
// no intermediate buffer, no producer pass.
__global__ __launch_bounds__(256) void k_gemm5(const float* __restrict__ V,
                                               const float* __restrict__ ws_in,
                                               float* __restrict__ logits,
                                               float* __restrict__ ws) {
    __shared__ f32x4 sAcc[2][64][4];      // 8KB: partner-wave accumulators
    int tid = threadIdx.x;
    int lane = tid & 63, w = tid >> 6;
    int ctl = w >> 1, kh = w & 1;         // ct-local, k-half
    int ct = blockIdx.x * 2 + ctl;        // 0..6249, all fully valid
    int g = lane >> 4, c4 = lane & 15;

    // lane reads V[ct*16+c4][(kh*4+ksl)*32 + g*8 .. +8], ksl=0..3
    const f32x4* __restrict__ vp =
        (const f32x4*)V + (size_t)(ct * 16 + c4) * 64 + kh * 32 + g * 2;
    f32x4 bv[4][2];
#pragma unroll
    for (int ksl = 0; ksl < 4; ++ksl) {
        bv[ksl][0] = vp[ksl * 8];
        bv[ksl][1] = vp[ksl * 8 + 1];
    }

    const short8* __restrict__ ap = (const short8*)(ws_in + W_A) + lane;
    f32x4 acc[4];
#pragma unroll
    for (int mt = 0; mt < 4; ++mt) acc[mt] = (f32x4){0.f, 0.f, 0.f, 0.f};
#pragma unroll
    for (int ksl = 0; ksl < 4; ++ksl) {
        short8 bf = pack8v(bv[ksl][0], bv[ksl][1]);
#pragma unroll
        for (int mt = 0; mt < 4; ++mt) {
            short8 a = ap[(mt * 8 + kh * 4 + ksl) * 64];   // L1-hot, coalesced
            acc[mt] = __builtin_amdgcn_mfma_f32_16x16x32_bf16(a, bf, acc[mt],
                                                              0, 0, 0);
        }
    }

    // ---- combine k-halves via LDS ----
    if (kh == 1) {
#pragma unroll
        for (int mt = 0; mt < 4; ++mt) sAcc[ctl][lane][mt] = acc[mt];
    }
    __syncthreads();
    if (kh == 1) return;
#pragma unroll
    for (int mt = 0; mt < 4; ++mt) {
        f32x4 o = sAcc[ctl][lane][mt];
        acc[mt][0] += o[0]; acc[mt][1] += o[1];
        acc[mt][2] += o[2]; acc[mt][3] += o[3];
    }

    // ---- epilogue: stores + per-ct exp partials ----
    int col = ct * 16 + c4;
    float* __restrict__ P = ws + W_PART + (size_t)ct * 64;
#pragma unroll
    for (int mt = 0; mt < 4; ++mt)
#pragma unroll
        for (int r = 0; r < 4; ++r) {
            int row = mt * 16 + g * 4 + r;
            float lg = acc[mt][r];
            logits[(size_t)row * CC + col] = lg;
            float e = expf(lg);                    // |logit| <= ~19, safe
            e += __shfl_xor(e, 1, 64); e += __shfl_xor(e, 2, 64);
            e += __shfl_xor(e, 4, 64); e += __shfl_xor(e, 8, 64);
            if (c4 == 0) P[row] = e;               // deterministic
        }
}

// 64 blocks (one per batch row): deterministic reduce of exp partials
__global__ __launch_bounds__(256) void k_comb(const float* __restrict__ ws_in,
                                              float* __restrict__ ws) {
    __shared__ float sS[256];
    int row = blockIdx.x;
    int tid = threadIdx.x;
    const float* __restrict__ P = ws_in + W_PART;
    float s = 0.f;
    for (int b = tid; b < NCT; b += 256) s += P[(size_t)b * 64 + row];
    sS[tid] = s;
    __syncthreads();
    if (tid < 128) sS[tid] += sS[tid + 128];
    __syncthreads();
    if (tid < 64) {
        float v = sS[tid] + sS[tid + 64];
        v = wredf(v);
        if (tid == 0) ws[W_SE + row] = v;
    }
}

// 1 block x 256 threads: G in LDS, masks as per-lane 64-bit registers
__global__ __launch_bounds__(256) void k_final(const int* __restrict__ targets,
                                               const void* __restrict__ pmask,
                                               const void* __restrict__ nmask,
                                               const float* __restrict__ logits,
                                               const float* __restrict__ ws,
                                               float* __restrict__ out) {
    __shared__ float sG[4096];
    int tid = threadIdx.x;
    float myLogit = 0.f, mySe = 0.f;
    if (tid < 64) {
        int tgt = targets[tid];
        myLogit = logits[(size_t)tid * CC + tgt];
        mySe = ws[W_SE + tid];
    }
    {
        const float4* __restrict__ G4 = (const float4*)(ws + W_GRAM);
        float4* sG4 = (float4*)sG;
#pragma unroll
        for (int i = 0; i < 4; ++i) sG4[tid + i * 256] = G4[tid + i * 256];
    }
    __syncthreads();
    if (tid >= 64) return;
    int lane = tid;

    // mode detect (identical semantics to all prior rounds)
    const unsigned int* pw = (const unsigned int*)pmask;
    int okInt = 1, okFlt = 1;
#pragma unroll
    for (int i = 0; i < 16; ++i) {
        unsigned int wv = pw[lane * 16 + i];
        okInt = okInt && (wv <= 1u);
        okFlt = okFlt && (wv == 0u || wv == 0x3f800000u);
    }
    int mode = __all(okInt) ? 0 : (__all(okFlt) ? 1 : 2);

    // pack masks into per-lane 64-bit registers (no memory in j-loops)
    unsigned long long pmb = 0ull, nmb = 0ull;
    for (int j = 0; j < 64; ++j) {
        if (mask_at(pmask, lane * 64 + j, mode)) pmb |= 1ull << j;
        if (mask_at(nmask, lane * 64 + j, mode)) nmb |= 1ull << j;
    }

    float lse = logf(mySe);
    float nll = lse - myLogit;
    float rinv = rsqrtf(sG[lane * 64 + lane]);

    float minp = INFINITY, maxthd = -INFINITY;
    for (int j = 0; j < 64; ++j) {
        float rj = __shfl(rinv, j, 64);
        float sim = sG[lane * 64 + j] * rinv * rj;
        sim = fminf(1.f, fmaxf(-1.f, sim));
        if (j != lane) {
            bool pm = (pmb >> j) & 1ull;
            float ps = pm ? sim : 2.0f;
            minp = fminf(minp, ps);
            maxthd = fmaxf(maxthd, pm ? sim : -2.0f);   // sentinel 2.0 -> -2.0
        }
    }
    float n_thrd = minp - NMARG;
    float p_thrd = maxthd - PMARG;

    float hps = 0.f, hns = 0.f, hpc = 0.f, hnc = 0.f;
    for (int j = 0; j < 64; ++j) {
        float rj = __shfl(rinv, j, 64);
        float sim = sG[lane * 64 + j] * rinv * rj;
        sim = fminf(1.f, fmaxf(-1.f, sim));
        if (j != lane) {
            bool pm = (pmb >> j) & 1ull;
            bool nm = (nmb >> j) & 1ull;
            float ps = pm ? sim : 2.0f;
            float ns = nm ? sim : 2.0f;
            if (ps < p_thrd) { hps += log1pf(expf(-ps)); hpc += 1.f; }
            if (ns < n_thrd) { hns += log1pf(expf(-ns)); hnc += 1.f; }
        }
    }

    float snll = wredf(nll);
    float shps = wredf(hps);
    float shns = wredf(hns);
    float shpc = wredf(hpc);
    float shnc = wredf(hnc);
    if (lane == 0) {
        float bu = snll * (1.f / 64.f);
        float hp = shpc > 0.f ? shps / shpc : 0.f;
        float hn = shnc > 0.f ? shns / shnc : 0.f;
        out[0] = bu + hp + hn;
    }
}

extern "C" void kernel_launch(void* const* d_in, const int* in_sizes, int n_in,
                              void* d_out, int out_size, void* d_ws, size_t ws_size,
                              hipStream_t stream) {
    const float* inputs = (const float*)d_in[0];
    const int* targets  = (const int*)d_in[1];
    const void* pmask   = d_in[2];
    const void* nmask   = d_in[3];
    const float* V      = (const float*)d_in[4];
    float* out = (float*)d_out;      // out[0] = loss
    float* logits = out + 1;         // out[1..] = logits [64][100000] row-major
    float* ws = (float*)d_ws;        // A-pack | Gram | se | per-ct partials

    hipLaunchKernelGGL(k_prep, dim3(65), dim3(256), 0, stream, inputs, ws);
    hipLaunchKernelGGL(k_gemm5, dim3(NGB), dim3(256), 0, stream,
                       V, ws, logits, ws);
    hipLaunchKernelGGL(k_comb, dim3(64), dim3(256), 0, stream, ws, ws);
    hipLaunchKernelGGL(k_final, dim3(1), dim3(256), 0, stream,
                       targets, pmask, nmask, logits, ws, out);
}